// Round 1
// baseline (1557.250 us; speedup 1.0000x reference)
//
#include <hip/hip_runtime.h>

#define D_IN 768
#define D_HID 256

// ---------------- CSR build ----------------

__global__ void k_count(const int* __restrict__ dst, int* __restrict__ deg, int E) {
    int i = blockIdx.x * 256 + threadIdx.x;
    if (i < E) atomicAdd(&deg[dst[i]], 1);
}

__global__ void k_dinv(const int* __restrict__ deg, float* __restrict__ dinv, int N) {
    int i = blockIdx.x * 256 + threadIdx.x;
    if (i < N) dinv[i] = rsqrtf((float)deg[i] + 1.0f);
}

// single-block scan over N elements -> exclusive prefix (row_ptr), row_ptr[N]=total
__global__ __launch_bounds__(1024) void k_scan(const int* __restrict__ deg,
                                               int* __restrict__ row_ptr, int N) {
    __shared__ int wsum[16];
    __shared__ int carry_s;
    int t = threadIdx.x;
    int lane = t & 63, wid = t >> 6;
    if (t == 0) carry_s = 0;
    __syncthreads();
    for (int base = 0; base < N; base += 1024) {
        int i = base + t;
        int v = (i < N) ? deg[i] : 0;
        int s = v;
        #pragma unroll
        for (int d = 1; d < 64; d <<= 1) {
            int tmp = __shfl_up(s, d);
            if (lane >= d) s += tmp;
        }
        if (lane == 63) wsum[wid] = s;
        __syncthreads();
        if (wid == 0 && lane < 16) {
            int ws = wsum[lane];
            #pragma unroll
            for (int d = 1; d < 16; d <<= 1) {
                int tmp = __shfl_up(ws, d);
                if (lane >= d) ws += tmp;
            }
            wsum[lane] = ws;  // inclusive over wave sums
        }
        __syncthreads();
        int carry = carry_s;
        int woff = (wid > 0) ? wsum[wid - 1] : 0;
        if (i < N) row_ptr[i] = carry + woff + s - v;
        __syncthreads();
        if (t == 0) carry_s = carry + wsum[15];
        __syncthreads();
    }
    if (t == 0) row_ptr[N] = carry_s;
}

__global__ void k_fill(const int* __restrict__ src, const int* __restrict__ dst,
                       const int* __restrict__ row_ptr, int* __restrict__ wptr,
                       int* __restrict__ csr_src, int E) {
    int i = blockIdx.x * 256 + threadIdx.x;
    if (i < E) {
        int d = dst[i];
        int w = atomicAdd(&wptr[d], 1);
        csr_src[row_ptr[d] + w] = src[i];
    }
}

__global__ void k_cnt_batch(const int* __restrict__ batch, int* __restrict__ cnt, int N) {
    int i = blockIdx.x * 256 + threadIdx.x;
    if (i < N) atomicAdd(&cnt[batch[i]], 1);
}

__global__ void k_off(const int* __restrict__ cnt, int* __restrict__ offg, int G) {
    if (threadIdx.x == 0) {
        int s = 0;
        for (int g = 0; g < G; ++g) { offg[g] = s; s += cnt[g]; }
    }
}

// ---------------- fp32 tiled GEMM: C[M,256] = A[M,K] @ B[K,256] ----------------
// BM=64, BN=64, BK=16, 256 threads, 4x4 per thread.

__global__ __launch_bounds__(256) void k_gemm(const float* __restrict__ A,
                                              const float* __restrict__ B,
                                              float* __restrict__ C,
                                              int M, int K, int N) {
    __shared__ __align__(16) float As[16][68];  // [k][m], pad 68 keeps 16B alignment
    __shared__ __align__(16) float Bs[16][68];  // [k][n]

    int t  = threadIdx.x;
    int tx = t & 15, ty = t >> 4;
    int bm = blockIdx.x * 64;
    int bn = blockIdx.y * 64;

    float acc[4][4] = {{0.f}};

    for (int k0 = 0; k0 < K; k0 += 16) {
        // A tile 64x16, one float4 per thread, transposed into As
        {
            int r = t >> 2, c = (t & 3) * 4;
            int gr = bm + r;
            float4 v = make_float4(0.f, 0.f, 0.f, 0.f);
            if (gr < M) v = *(const float4*)&A[(size_t)gr * K + k0 + c];
            As[c + 0][r] = v.x;
            As[c + 1][r] = v.y;
            As[c + 2][r] = v.z;
            As[c + 3][r] = v.w;
        }
        // B tile 16x64, one float4 per thread
        {
            int r = t >> 4, c = (t & 15) * 4;
            float4 v = *(const float4*)&B[(size_t)(k0 + r) * N + bn + c];
            *(float4*)&Bs[r][c] = v;
        }
        __syncthreads();
        #pragma unroll
        for (int k = 0; k < 16; ++k) {
            float4 a = *(const float4*)&As[k][ty * 4];
            float4 b = *(const float4*)&Bs[k][tx * 4];
            float av[4] = {a.x, a.y, a.z, a.w};
            float bv[4] = {b.x, b.y, b.z, b.w};
            #pragma unroll
            for (int i = 0; i < 4; ++i)
                #pragma unroll
                for (int j = 0; j < 4; ++j)
                    acc[i][j] = fmaf(av[i], bv[j], acc[i][j]);
        }
        __syncthreads();
    }

    #pragma unroll
    for (int i = 0; i < 4; ++i) {
        int gr = bm + ty * 4 + i;
        if (gr < M) {
            float4 v = make_float4(acc[i][0], acc[i][1], acc[i][2], acc[i][3]);
            *(float4*)&C[(size_t)gr * N + bn + tx * 4] = v;
        }
    }
}

// ---------------- aggregation: out[i] = dinv_i * sum_{e:dst=i} dinv_src h[src] + dinv_i^2 h[i] + b
template <int RELU>
__global__ __launch_bounds__(256) void k_agg(const float* __restrict__ hin,
                                             float* __restrict__ hout,
                                             const int* __restrict__ row_ptr,
                                             const int* __restrict__ csr_src,
                                             const float* __restrict__ dinv,
                                             const float* __restrict__ bias) {
    int row = blockIdx.x;
    int c = threadIdx.x;
    int s = row_ptr[row], e = row_ptr[row + 1];
    float acc = 0.f;
    for (int j = s; j < e; ++j) {
        int u = csr_src[j];
        acc += dinv[u] * hin[(size_t)u * D_HID + c];
    }
    float di = dinv[row];
    acc = acc * di + di * di * hin[(size_t)row * D_HID + c] + bias[c];
    if (RELU) acc = fmaxf(acc, 0.f);
    hout[(size_t)row * D_HID + c] = acc;
}

// ---------------- pool (partial sums with atomics into zeroed g) ----------------
__global__ __launch_bounds__(256) void k_pool(const float* __restrict__ h,
                                              const int* __restrict__ cnt,
                                              const int* __restrict__ offg,
                                              float* __restrict__ g) {
    int gi = blockIdx.x, slice = blockIdx.y;
    int c = threadIdx.x;
    int start = offg[gi], n = cnt[gi];
    int per = (n + (int)gridDim.y - 1) / (int)gridDim.y;
    int r0 = slice * per;
    int r1 = min(n, r0 + per);
    float acc = 0.f;
    for (int r = r0; r < r1; ++r) acc += h[(size_t)(start + r) * D_HID + c];
    if (r1 > r0) atomicAdd(&g[gi * D_HID + c], acc);
}

// ---------------- head: out[G,768] = (g/cnt) @ Wl + bl ----------------
__global__ __launch_bounds__(256) void k_final(const float* __restrict__ g,
                                               const int* __restrict__ cnt,
                                               const float* __restrict__ Wl,
                                               const float* __restrict__ bl,
                                               float* __restrict__ out) {
    __shared__ float gs[D_HID];
    int t = threadIdx.x;
    int gi = blockIdx.y;
    int c = blockIdx.x * 256 + t;
    float inv = 1.0f / (float)max(cnt[gi], 1);
    gs[t] = g[gi * D_HID + t] * inv;
    __syncthreads();
    float acc = bl[c];
    #pragma unroll 8
    for (int k = 0; k < D_HID; ++k) acc = fmaf(gs[k], Wl[(size_t)k * D_IN + c], acc);
    out[(size_t)gi * D_IN + c] = acc;
}

// ---------------- launch ----------------

extern "C" void kernel_launch(void* const* d_in, const int* in_sizes, int n_in,
                              void* d_out, int out_size, void* d_ws, size_t ws_size,
                              hipStream_t stream) {
    const float* x     = (const float*)d_in[0];
    const int*   ei    = (const int*)d_in[1];
    const int*   batch = (const int*)d_in[2];
    const float* W1 = (const float*)d_in[3];
    const float* b1 = (const float*)d_in[4];
    const float* W2 = (const float*)d_in[5];
    const float* b2 = (const float*)d_in[6];
    const float* W3 = (const float*)d_in[7];
    const float* b3 = (const float*)d_in[8];
    const float* Wl = (const float*)d_in[9];
    const float* bl = (const float*)d_in[10];
    float* out = (float*)d_out;

    int N = in_sizes[2];
    int E = in_sizes[1] / 2;
    int G = out_size / D_IN;
    const int* srcp = ei;
    const int* dstp = ei + E;

    char* ws = (char*)d_ws;
    size_t o = 0;
    auto alloc = [&](size_t bytes) -> char* {
        char* p = ws + o;
        o += (bytes + 255) & ~(size_t)255;
        return p;
    };
    int*   deg     = (int*)alloc((size_t)N * 4);
    int*   wptr    = (int*)alloc((size_t)N * 4);
    int*   row_ptr = (int*)alloc((size_t)(N + 1) * 4);
    int*   cnt     = (int*)alloc((size_t)G * 4);
    int*   offg    = (int*)alloc((size_t)G * 4);
    int*   csr_src = (int*)alloc((size_t)E * 4);
    float* dinv    = (float*)alloc((size_t)N * 4);
    float* gbuf    = (float*)alloc((size_t)G * D_HID * 4);
    float* hA      = (float*)alloc((size_t)N * D_HID * 4);
    float* hB      = (float*)alloc((size_t)N * D_HID * 4);

    hipMemsetAsync(deg, 0, (size_t)N * 4, stream);
    hipMemsetAsync(wptr, 0, (size_t)N * 4, stream);
    hipMemsetAsync(cnt, 0, (size_t)G * 4, stream);
    hipMemsetAsync(gbuf, 0, (size_t)G * D_HID * 4, stream);

    int gE = (E + 255) / 256;
    int gN = (N + 255) / 256;

    k_count<<<gE, 256, 0, stream>>>(dstp, deg, E);
    k_dinv<<<gN, 256, 0, stream>>>(deg, dinv, N);
    k_scan<<<1, 1024, 0, stream>>>(deg, row_ptr, N);
    k_fill<<<gE, 256, 0, stream>>>(srcp, dstp, row_ptr, wptr, csr_src, E);
    k_cnt_batch<<<gN, 256, 0, stream>>>(batch, cnt, N);
    k_off<<<1, 64, 0, stream>>>(cnt, offg, G);

    dim3 gemm_grid((N + 63) / 64, D_HID / 64);

    // layer 1
    k_gemm<<<gemm_grid, 256, 0, stream>>>(x, W1, hA, N, D_IN, D_HID);
    k_agg<1><<<N, 256, 0, stream>>>(hA, hB, row_ptr, csr_src, dinv, b1);
    // layer 2
    k_gemm<<<gemm_grid, 256, 0, stream>>>(hB, W2, hA, N, D_HID, D_HID);
    k_agg<1><<<N, 256, 0, stream>>>(hA, hB, row_ptr, csr_src, dinv, b2);
    // layer 3
    k_gemm<<<gemm_grid, 256, 0, stream>>>(hB, W3, hA, N, D_HID, D_HID);
    k_agg<0><<<N, 256, 0, stream>>>(hA, hB, row_ptr, csr_src, dinv, b3);

    // pool + head
    dim3 pool_grid(G, 8);
    k_pool<<<pool_grid, 256, 0, stream>>>(hB, cnt, offg, gbuf);
    dim3 fin_grid(D_IN / 256, G);
    k_final<<<fin_grid, 256, 0, stream>>>(gbuf, cnt, Wl, bl, out);
}

// Round 3
// 1322.939 us; speedup vs baseline: 1.1771x; 1.1771x over previous
//
#include <hip/hip_runtime.h>
#include <hip/hip_bf16.h>

#define D_IN 768
#define D_HID 256

typedef __attribute__((ext_vector_type(8))) short short8;
typedef __attribute__((ext_vector_type(4))) float f32x4;

// ---------------- CSR build ----------------

__global__ void k_count(const int* __restrict__ dst, int* __restrict__ deg, int E) {
    int i = blockIdx.x * 256 + threadIdx.x;
    if (i < E) atomicAdd(&deg[dst[i]], 1);
}

__global__ void k_dinv(const int* __restrict__ deg, float* __restrict__ dinv, int N) {
    int i = blockIdx.x * 256 + threadIdx.x;
    if (i < N) dinv[i] = rsqrtf((float)deg[i] + 1.0f);
}

// single-block scan over N elements -> exclusive prefix (row_ptr), row_ptr[N]=total
__global__ __launch_bounds__(1024) void k_scan(const int* __restrict__ deg,
                                               int* __restrict__ row_ptr, int N) {
    __shared__ int wsum[16];
    __shared__ int carry_s;
    int t = threadIdx.x;
    int lane = t & 63, wid = t >> 6;
    if (t == 0) carry_s = 0;
    __syncthreads();
    for (int base = 0; base < N; base += 1024) {
        int i = base + t;
        int v = (i < N) ? deg[i] : 0;
        int s = v;
        #pragma unroll
        for (int d = 1; d < 64; d <<= 1) {
            int tmp = __shfl_up(s, d);
            if (lane >= d) s += tmp;
        }
        if (lane == 63) wsum[wid] = s;
        __syncthreads();
        if (wid == 0 && lane < 16) {
            int ws = wsum[lane];
            #pragma unroll
            for (int d = 1; d < 16; d <<= 1) {
                int tmp = __shfl_up(ws, d);
                if (lane >= d) ws += tmp;
            }
            wsum[lane] = ws;  // inclusive over wave sums
        }
        __syncthreads();
        int carry = carry_s;
        int woff = (wid > 0) ? wsum[wid - 1] : 0;
        if (i < N) row_ptr[i] = carry + woff + s - v;
        __syncthreads();
        if (t == 0) carry_s = carry + wsum[15];
        __syncthreads();
    }
    if (t == 0) row_ptr[N] = carry_s;
}

__global__ void k_fill(const int* __restrict__ src, const int* __restrict__ dst,
                       const int* __restrict__ row_ptr, int* __restrict__ wptr,
                       int* __restrict__ csr_src, int E) {
    int i = blockIdx.x * 256 + threadIdx.x;
    if (i < E) {
        int d = dst[i];
        int w = atomicAdd(&wptr[d], 1);
        csr_src[row_ptr[d] + w] = src[i];
    }
}

__global__ void k_cnt_batch(const int* __restrict__ batch, int* __restrict__ cnt, int N) {
    int i = blockIdx.x * 256 + threadIdx.x;
    if (i < N) atomicAdd(&cnt[batch[i]], 1);
}

__global__ void k_off(const int* __restrict__ cnt, int* __restrict__ offg, int G) {
    if (threadIdx.x == 0) {
        int s = 0;
        for (int g = 0; g < G; ++g) { offg[g] = s; s += cnt[g]; }
    }
}

// ---------------- B prep: fp32 [K][256] -> swizzled bf16 hi/lo fragment order ----
// layout: elem offset = ((c*2 + f)*4 + q)*2048 + n*8 + j
//   where k = c*32 + q*8 + j (c=k-chunk, q=lane>>4 group, j=within-frag)
__global__ void k_prep_B(const float* __restrict__ B, short* __restrict__ Bp, int K) {
    int t = blockIdx.x * 256 + threadIdx.x;
    if (t >= K * 256) return;
    int k = t >> 8, n = t & 255;
    float v = B[(size_t)k * 256 + n];
    __hip_bfloat16 h = __float2bfloat16(v);
    float hf = __bfloat162float(h);
    float r = v - hf;
    __hip_bfloat16 l = __float2bfloat16(r);
    int c = k >> 5, q = (k >> 3) & 3, j = k & 7;
    size_t oh = ((size_t)(c * 2 + 0) * 4 + q) * 2048 + n * 8 + j;
    size_t ol = ((size_t)(c * 2 + 1) * 4 + q) * 2048 + n * 8 + j;
    Bp[oh] = *(short*)&h;
    Bp[ol] = *(short*)&l;
}

// ---------------- MFMA GEMM: C[M,256] = A[M,K] @ B[K,256], split-bf16 fp32 emu ---
// BM=64 (4 waves x 16-row strips), BN=256 (full width), BK=32.
__global__ __launch_bounds__(256) void k_gemm_mfma(const float* __restrict__ A,
                                                   const short* __restrict__ Bp,
                                                   float* __restrict__ C,
                                                   int M, int K) {
    __shared__ short Bs[16384];  // 32 KB per chunk: [f(2)][q(4)][n(256)][j(8)]
    int t = threadIdx.x;
    int lane = t & 63, w = t >> 6;
    int ln = lane & 15, q = lane >> 4;
    int bm = blockIdx.x * 64;
    int m_g = bm + w * 16 + ln;
    bool valid = m_g < M;
    const float* Arow = A + (size_t)(valid ? m_g : 0) * K;

    f32x4 acc[16];
    #pragma unroll
    for (int i = 0; i < 16; ++i) acc[i] = (f32x4){0.f, 0.f, 0.f, 0.f};

    int nchunks = K >> 5;
    for (int c = 0; c < nchunks; ++c) {
        __syncthreads();
        // stage B chunk: 32 KB = 8 iterations x 256 threads x 16 B, fully coalesced
        {
            const short* srcp = Bp + (size_t)c * 16384;
            #pragma unroll
            for (int i = 0; i < 8; ++i) {
                int s = (t + i * 256) * 8;
                *(short8*)&Bs[s] = *(const short8*)&srcp[s];
            }
        }
        // A fragment: 8 contiguous floats, split to bf16 hi/lo in-register
        float av[8];
        if (valid) {
            float4 v0 = *(const float4*)&Arow[c * 32 + q * 8];
            float4 v1 = *(const float4*)&Arow[c * 32 + q * 8 + 4];
            av[0] = v0.x; av[1] = v0.y; av[2] = v0.z; av[3] = v0.w;
            av[4] = v1.x; av[5] = v1.y; av[6] = v1.z; av[7] = v1.w;
        } else {
            #pragma unroll
            for (int i = 0; i < 8; ++i) av[i] = 0.f;
        }
        short8 a_hi, a_lo;
        #pragma unroll
        for (int i = 0; i < 8; ++i) {
            __hip_bfloat16 h = __float2bfloat16(av[i]);
            float hf = __bfloat162float(h);
            __hip_bfloat16 l = __float2bfloat16(av[i] - hf);
            a_hi[i] = *(short*)&h;
            a_lo[i] = *(short*)&l;
        }
        __syncthreads();
        #pragma unroll
        for (int tt = 0; tt < 16; ++tt) {
            short8 b_hi = *(const short8*)&Bs[(0 * 4 + q) * 2048 + (tt * 16 + ln) * 8];
            short8 b_lo = *(const short8*)&Bs[(1 * 4 + q) * 2048 + (tt * 16 + ln) * 8];
            acc[tt] = __builtin_amdgcn_mfma_f32_16x16x32_bf16(a_hi, b_hi, acc[tt], 0, 0, 0);
            acc[tt] = __builtin_amdgcn_mfma_f32_16x16x32_bf16(a_hi, b_lo, acc[tt], 0, 0, 0);
            acc[tt] = __builtin_amdgcn_mfma_f32_16x16x32_bf16(a_lo, b_hi, acc[tt], 0, 0, 0);
        }
    }
    // C/D layout: col = tt*16 + (lane&15), row = w*16 + (lane>>4)*4 + r
    #pragma unroll
    for (int tt = 0; tt < 16; ++tt) {
        #pragma unroll
        for (int r = 0; r < 4; ++r) {
            int row = bm + w * 16 + q * 4 + r;
            if (row < M) C[(size_t)row * 256 + tt * 16 + ln] = acc[tt][r];
        }
    }
}

// ---------------- aggregation ----------------
template <int RELU>
__global__ __launch_bounds__(256) void k_agg(const float* __restrict__ hin,
                                             float* __restrict__ hout,
                                             const int* __restrict__ row_ptr,
                                             const int* __restrict__ csr_src,
                                             const float* __restrict__ dinv,
                                             const float* __restrict__ bias) {
    int row = blockIdx.x;
    int c = threadIdx.x;
    int s = row_ptr[row], e = row_ptr[row + 1];
    float acc = 0.f;
    for (int j = s; j < e; ++j) {
        int u = csr_src[j];
        acc += dinv[u] * hin[(size_t)u * D_HID + c];
    }
    float di = dinv[row];
    acc = acc * di + di * di * hin[(size_t)row * D_HID + c] + bias[c];
    if (RELU) acc = fmaxf(acc, 0.f);
    hout[(size_t)row * D_HID + c] = acc;
}

// ---------------- pool ----------------
__global__ __launch_bounds__(256) void k_pool(const float* __restrict__ h,
                                              const int* __restrict__ cnt,
                                              const int* __restrict__ offg,
                                              float* __restrict__ g) {
    int gi = blockIdx.x, slice = blockIdx.y;
    int c = threadIdx.x;
    int start = offg[gi], n = cnt[gi];
    int per = (n + (int)gridDim.y - 1) / (int)gridDim.y;
    int r0 = slice * per;
    int r1 = min(n, r0 + per);
    float acc = 0.f;
    for (int r = r0; r < r1; ++r) acc += h[(size_t)(start + r) * D_HID + c];
    if (r1 > r0) atomicAdd(&g[gi * D_HID + c], acc);
}

// ---------------- head ----------------
__global__ __launch_bounds__(256) void k_final(const float* __restrict__ g,
                                               const int* __restrict__ cnt,
                                               const float* __restrict__ Wl,
                                               const float* __restrict__ bl,
                                               float* __restrict__ out) {
    __shared__ float gs[D_HID];
    int t = threadIdx.x;
    int gi = blockIdx.y;
    int c = blockIdx.x * 256 + t;
    float inv = 1.0f / (float)max(cnt[gi], 1);
    gs[t] = g[gi * D_HID + t] * inv;
    __syncthreads();
    float acc = bl[c];
    #pragma unroll 8
    for (int k = 0; k < D_HID; ++k) acc = fmaf(gs[k], Wl[(size_t)k * D_IN + c], acc);
    out[(size_t)gi * D_IN + c] = acc;
}

// ---------------- launch ----------------

extern "C" void kernel_launch(void* const* d_in, const int* in_sizes, int n_in,
                              void* d_out, int out_size, void* d_ws, size_t ws_size,
                              hipStream_t stream) {
    const float* x     = (const float*)d_in[0];
    const int*   ei    = (const int*)d_in[1];
    const int*   batch = (const int*)d_in[2];
    const float* W1 = (const float*)d_in[3];
    const float* b1 = (const float*)d_in[4];
    const float* W2 = (const float*)d_in[5];
    const float* b2 = (const float*)d_in[6];
    const float* W3 = (const float*)d_in[7];
    const float* b3 = (const float*)d_in[8];
    const float* Wl = (const float*)d_in[9];
    const float* bl = (const float*)d_in[10];
    float* out = (float*)d_out;

    int N = in_sizes[2];
    int E = in_sizes[1] / 2;
    int G = out_size / D_IN;
    const int* srcp = ei;
    const int* dstp = ei + E;

    char* ws = (char*)d_ws;
    size_t o = 0;
    auto alloc = [&](size_t bytes) -> char* {
        char* p = ws + o;
        o += (bytes + 255) & ~(size_t)255;
        return p;
    };
    int*   deg     = (int*)alloc((size_t)N * 4);
    int*   wptr    = (int*)alloc((size_t)N * 4);
    int*   row_ptr = (int*)alloc((size_t)(N + 1) * 4);
    int*   cnt     = (int*)alloc((size_t)G * 4);
    int*   offg    = (int*)alloc((size_t)G * 4);
    int*   csr_src = (int*)alloc((size_t)E * 4);
    float* dinv    = (float*)alloc((size_t)N * 4);
    float* gbuf    = (float*)alloc((size_t)G * D_HID * 4);
    float* hA      = (float*)alloc((size_t)N * D_HID * 4);
    float* hB      = (float*)alloc((size_t)N * D_HID * 4);
    short* Bp1     = (short*)alloc((size_t)D_IN * 512 * 2);   // K=768 swizzled hi/lo
    short* Bp2     = (short*)alloc((size_t)D_HID * 512 * 2);  // K=256
    short* Bp3     = (short*)alloc((size_t)D_HID * 512 * 2);

    hipMemsetAsync(deg, 0, (size_t)N * 4, stream);
    hipMemsetAsync(wptr, 0, (size_t)N * 4, stream);
    hipMemsetAsync(cnt, 0, (size_t)G * 4, stream);
    hipMemsetAsync(gbuf, 0, (size_t)G * D_HID * 4, stream);

    int gE = (E + 255) / 256;
    int gN = (N + 255) / 256;

    k_count<<<gE, 256, 0, stream>>>(dstp, deg, E);
    k_dinv<<<gN, 256, 0, stream>>>(deg, dinv, N);
    k_scan<<<1, 1024, 0, stream>>>(deg, row_ptr, N);
    k_fill<<<gE, 256, 0, stream>>>(srcp, dstp, row_ptr, wptr, csr_src, E);
    k_cnt_batch<<<gN, 256, 0, stream>>>(batch, cnt, N);
    k_off<<<1, 64, 0, stream>>>(cnt, offg, G);

    k_prep_B<<<D_IN, 256, 0, stream>>>(W1, Bp1, D_IN);
    k_prep_B<<<D_HID, 256, 0, stream>>>(W2, Bp2, D_HID);
    k_prep_B<<<D_HID, 256, 0, stream>>>(W3, Bp3, D_HID);

    int gemm_grid = (N + 63) / 64;

    // layer 1
    k_gemm_mfma<<<gemm_grid, 256, 0, stream>>>(x, Bp1, hA, N, D_IN);
    k_agg<1><<<N, 256, 0, stream>>>(hA, hB, row_ptr, csr_src, dinv, b1);
    // layer 2
    k_gemm_mfma<<<gemm_grid, 256, 0, stream>>>(hB, Bp2, hA, N, D_HID);
    k_agg<1><<<N, 256, 0, stream>>>(hA, hB, row_ptr, csr_src, dinv, b2);
    // layer 3
    k_gemm_mfma<<<gemm_grid, 256, 0, stream>>>(hB, Bp3, hA, N, D_HID);
    k_agg<0><<<N, 256, 0, stream>>>(hA, hB, row_ptr, csr_src, dinv, b3);

    // pool + head
    dim3 pool_grid(G, 8);
    k_pool<<<pool_grid, 256, 0, stream>>>(hB, cnt, offg, gbuf);
    dim3 fin_grid(D_IN / 256, G);
    k_final<<<fin_grid, 256, 0, stream>>>(gbuf, cnt, Wl, bl, out);
}

// Round 4
// 1094.433 us; speedup vs baseline: 1.4229x; 1.2088x over previous
//
#include <hip/hip_runtime.h>
#include <hip/hip_bf16.h>

#define D_IN 768
#define D_HID 256

typedef __attribute__((ext_vector_type(8))) short short8;
typedef __attribute__((ext_vector_type(4))) float f32x4;

// ---------------- CSR build ----------------

__global__ void k_count(const int* __restrict__ dst, int* __restrict__ deg, int E) {
    int i = blockIdx.x * 256 + threadIdx.x;
    if (i < E) atomicAdd(&deg[dst[i]], 1);
}

__global__ void k_dinv(const int* __restrict__ deg, float* __restrict__ dinv, int N) {
    int i = blockIdx.x * 256 + threadIdx.x;
    if (i < N) dinv[i] = rsqrtf((float)deg[i] + 1.0f);
}

// single-block scan over N elements -> exclusive prefix (row_ptr), row_ptr[N]=total
__global__ __launch_bounds__(1024) void k_scan(const int* __restrict__ deg,
                                               int* __restrict__ row_ptr, int N) {
    __shared__ int wsum[16];
    __shared__ int carry_s;
    int t = threadIdx.x;
    int lane = t & 63, wid = t >> 6;
    if (t == 0) carry_s = 0;
    __syncthreads();
    for (int base = 0; base < N; base += 1024) {
        int i = base + t;
        int v = (i < N) ? deg[i] : 0;
        int s = v;
        #pragma unroll
        for (int d = 1; d < 64; d <<= 1) {
            int tmp = __shfl_up(s, d);
            if (lane >= d) s += tmp;
        }
        if (lane == 63) wsum[wid] = s;
        __syncthreads();
        if (wid == 0 && lane < 16) {
            int ws = wsum[lane];
            #pragma unroll
            for (int d = 1; d < 16; d <<= 1) {
                int tmp = __shfl_up(ws, d);
                if (lane >= d) ws += tmp;
            }
            wsum[lane] = ws;  // inclusive over wave sums
        }
        __syncthreads();
        int carry = carry_s;
        int woff = (wid > 0) ? wsum[wid - 1] : 0;
        if (i < N) row_ptr[i] = carry + woff + s - v;
        __syncthreads();
        if (t == 0) carry_s = carry + wsum[15];
        __syncthreads();
    }
    if (t == 0) row_ptr[N] = carry_s;
}

__global__ void k_fill(const int* __restrict__ src, const int* __restrict__ dst,
                       const int* __restrict__ row_ptr, int* __restrict__ wptr,
                       int* __restrict__ csr_src, int E) {
    int i = blockIdx.x * 256 + threadIdx.x;
    if (i < E) {
        int d = dst[i];
        int w = atomicAdd(&wptr[d], 1);
        csr_src[row_ptr[d] + w] = src[i];
    }
}

// batch is SORTED: graph boundaries via binary search — no atomics.
__global__ void k_bounds(const int* __restrict__ batch, int* __restrict__ cnt,
                         int* __restrict__ offg, int N, int G) {
    int g = threadIdx.x;
    if (g >= G) return;
    auto lower = [&](int key) {
        int lo = 0, hi = N;
        while (lo < hi) {
            int mid = (lo + hi) >> 1;
            if (batch[mid] < key) lo = mid + 1; else hi = mid;
        }
        return lo;
    };
    int lo = lower(g);
    int hi = lower(g + 1);
    offg[g] = lo;
    cnt[g] = hi - lo;
}

// ---------------- B prep: fp32 [K][256] -> swizzled bf16 hi/lo fragment order ----
// layout: elem offset = ((c*2 + f)*4 + q)*2048 + n*8 + j
//   where k = c*32 + q*8 + j (c=k-chunk, q=lane>>4 group, j=within-frag)
__global__ void k_prep_B(const float* __restrict__ B, short* __restrict__ Bp, int K) {
    int t = blockIdx.x * 256 + threadIdx.x;
    if (t >= K * 256) return;
    int k = t >> 8, n = t & 255;
    float v = B[(size_t)k * 256 + n];
    __hip_bfloat16 h = __float2bfloat16(v);
    float hf = __bfloat162float(h);
    float r = v - hf;
    __hip_bfloat16 l = __float2bfloat16(r);
    int c = k >> 5, q = (k >> 3) & 3, j = k & 7;
    size_t oh = ((size_t)(c * 2 + 0) * 4 + q) * 2048 + n * 8 + j;
    size_t ol = ((size_t)(c * 2 + 1) * 4 + q) * 2048 + n * 8 + j;
    Bp[oh] = *(short*)&h;
    Bp[ol] = *(short*)&l;
}

// ---------------- MFMA GEMM: C[M,256] = A[M,K] @ B[K,256], split-bf16 fp32 emu ---
// BM=64 (4 waves x 16-row strips), BN=256 (full width), BK=32.
__global__ __launch_bounds__(256) void k_gemm_mfma(const float* __restrict__ A,
                                                   const short* __restrict__ Bp,
                                                   float* __restrict__ C,
                                                   int M, int K) {
    __shared__ short Bs[16384];  // 32 KB per chunk: [f(2)][q(4)][n(256)][j(8)]
    int t = threadIdx.x;
    int lane = t & 63, w = t >> 6;
    int ln = lane & 15, q = lane >> 4;
    int bm = blockIdx.x * 64;
    int m_g = bm + w * 16 + ln;
    bool valid = m_g < M;
    const float* Arow = A + (size_t)(valid ? m_g : 0) * K;

    f32x4 acc[16];
    #pragma unroll
    for (int i = 0; i < 16; ++i) acc[i] = (f32x4){0.f, 0.f, 0.f, 0.f};

    int nchunks = K >> 5;
    for (int c = 0; c < nchunks; ++c) {
        __syncthreads();
        // stage B chunk: 32 KB = 8 iterations x 256 threads x 16 B, fully coalesced
        {
            const short* srcp = Bp + (size_t)c * 16384;
            #pragma unroll
            for (int i = 0; i < 8; ++i) {
                int s = (t + i * 256) * 8;
                *(short8*)&Bs[s] = *(const short8*)&srcp[s];
            }
        }
        // A fragment: 8 contiguous floats, split to bf16 hi/lo in-register
        float av[8];
        if (valid) {
            float4 v0 = *(const float4*)&Arow[c * 32 + q * 8];
            float4 v1 = *(const float4*)&Arow[c * 32 + q * 8 + 4];
            av[0] = v0.x; av[1] = v0.y; av[2] = v0.z; av[3] = v0.w;
            av[4] = v1.x; av[5] = v1.y; av[6] = v1.z; av[7] = v1.w;
        } else {
            #pragma unroll
            for (int i = 0; i < 8; ++i) av[i] = 0.f;
        }
        short8 a_hi, a_lo;
        #pragma unroll
        for (int i = 0; i < 8; ++i) {
            __hip_bfloat16 h = __float2bfloat16(av[i]);
            float hf = __bfloat162float(h);
            __hip_bfloat16 l = __float2bfloat16(av[i] - hf);
            a_hi[i] = *(short*)&h;
            a_lo[i] = *(short*)&l;
        }
        __syncthreads();
        #pragma unroll
        for (int tt = 0; tt < 16; ++tt) {
            short8 b_hi = *(const short8*)&Bs[(0 * 4 + q) * 2048 + (tt * 16 + ln) * 8];
            short8 b_lo = *(const short8*)&Bs[(1 * 4 + q) * 2048 + (tt * 16 + ln) * 8];
            acc[tt] = __builtin_amdgcn_mfma_f32_16x16x32_bf16(a_hi, b_hi, acc[tt], 0, 0, 0);
            acc[tt] = __builtin_amdgcn_mfma_f32_16x16x32_bf16(a_hi, b_lo, acc[tt], 0, 0, 0);
            acc[tt] = __builtin_amdgcn_mfma_f32_16x16x32_bf16(a_lo, b_hi, acc[tt], 0, 0, 0);
        }
    }
    // C/D layout: col = tt*16 + (lane&15), row = w*16 + (lane>>4)*4 + r
    #pragma unroll
    for (int tt = 0; tt < 16; ++tt) {
        #pragma unroll
        for (int r = 0; r < 4; ++r) {
            int row = bm + w * 16 + q * 4 + r;
            if (row < M) C[(size_t)row * 256 + tt * 16 + ln] = acc[tt][r];
        }
    }
}

// ---------------- aggregation ----------------
template <int RELU>
__global__ __launch_bounds__(256) void k_agg(const float* __restrict__ hin,
                                             float* __restrict__ hout,
                                             const int* __restrict__ row_ptr,
                                             const int* __restrict__ csr_src,
                                             const float* __restrict__ dinv,
                                             const float* __restrict__ bias) {
    int row = blockIdx.x;
    int c = threadIdx.x;
    int s = row_ptr[row], e = row_ptr[row + 1];
    float acc = 0.f;
    for (int j = s; j < e; ++j) {
        int u = csr_src[j];
        acc += dinv[u] * hin[(size_t)u * D_HID + c];
    }
    float di = dinv[row];
    acc = acc * di + di * di * hin[(size_t)row * D_HID + c] + bias[c];
    if (RELU) acc = fmaxf(acc, 0.f);
    hout[(size_t)row * D_HID + c] = acc;
}

// ---------------- pool ----------------
__global__ __launch_bounds__(256) void k_pool(const float* __restrict__ h,
                                              const int* __restrict__ cnt,
                                              const int* __restrict__ offg,
                                              float* __restrict__ g) {
    int gi = blockIdx.x, slice = blockIdx.y;
    int c = threadIdx.x;
    int start = offg[gi], n = cnt[gi];
    int per = (n + (int)gridDim.y - 1) / (int)gridDim.y;
    int r0 = slice * per;
    int r1 = min(n, r0 + per);
    float acc = 0.f;
    for (int r = r0; r < r1; ++r) acc += h[(size_t)(start + r) * D_HID + c];
    if (r1 > r0) atomicAdd(&g[gi * D_HID + c], acc);
}

// ---------------- head ----------------
__global__ __launch_bounds__(256) void k_final(const float* __restrict__ g,
                                               const int* __restrict__ cnt,
                                               const float* __restrict__ Wl,
                                               const float* __restrict__ bl,
                                               float* __restrict__ out) {
    __shared__ float gs[D_HID];
    int t = threadIdx.x;
    int gi = blockIdx.y;
    int c = blockIdx.x * 256 + t;
    float inv = 1.0f / (float)max(cnt[gi], 1);
    gs[t] = g[gi * D_HID + t] * inv;
    __syncthreads();
    float acc = bl[c];
    #pragma unroll 8
    for (int k = 0; k < D_HID; ++k) acc = fmaf(gs[k], Wl[(size_t)k * D_IN + c], acc);
    out[(size_t)gi * D_IN + c] = acc;
}

// ---------------- launch ----------------

extern "C" void kernel_launch(void* const* d_in, const int* in_sizes, int n_in,
                              void* d_out, int out_size, void* d_ws, size_t ws_size,
                              hipStream_t stream) {
    const float* x     = (const float*)d_in[0];
    const int*   ei    = (const int*)d_in[1];
    const int*   batch = (const int*)d_in[2];
    const float* W1 = (const float*)d_in[3];
    const float* b1 = (const float*)d_in[4];
    const float* W2 = (const float*)d_in[5];
    const float* b2 = (const float*)d_in[6];
    const float* W3 = (const float*)d_in[7];
    const float* b3 = (const float*)d_in[8];
    const float* Wl = (const float*)d_in[9];
    const float* bl = (const float*)d_in[10];
    float* out = (float*)d_out;

    int N = in_sizes[2];
    int E = in_sizes[1] / 2;
    int G = out_size / D_IN;
    const int* srcp = ei;
    const int* dstp = ei + E;

    char* ws = (char*)d_ws;
    size_t o = 0;
    auto alloc = [&](size_t bytes) -> char* {
        char* p = ws + o;
        o += (bytes + 255) & ~(size_t)255;
        return p;
    };
    int*   deg     = (int*)alloc((size_t)N * 4);
    int*   wptr    = (int*)alloc((size_t)N * 4);
    int*   row_ptr = (int*)alloc((size_t)(N + 1) * 4);
    int*   cnt     = (int*)alloc((size_t)G * 4);
    int*   offg    = (int*)alloc((size_t)G * 4);
    int*   csr_src = (int*)alloc((size_t)E * 4);
    float* dinv    = (float*)alloc((size_t)N * 4);
    float* gbuf    = (float*)alloc((size_t)G * D_HID * 4);
    float* hA      = (float*)alloc((size_t)N * D_HID * 4);
    float* hB      = (float*)alloc((size_t)N * D_HID * 4);
    short* Bp1     = (short*)alloc((size_t)D_IN * 512 * 2);   // K=768 swizzled hi/lo
    short* Bp2     = (short*)alloc((size_t)D_HID * 512 * 2);  // K=256
    short* Bp3     = (short*)alloc((size_t)D_HID * 512 * 2);

    hipMemsetAsync(deg, 0, (size_t)N * 4, stream);
    hipMemsetAsync(wptr, 0, (size_t)N * 4, stream);
    hipMemsetAsync(gbuf, 0, (size_t)G * D_HID * 4, stream);

    int gE = (E + 255) / 256;
    int gN = (N + 255) / 256;

    k_count<<<gE, 256, 0, stream>>>(dstp, deg, E);
    k_dinv<<<gN, 256, 0, stream>>>(deg, dinv, N);
    k_scan<<<1, 1024, 0, stream>>>(deg, row_ptr, N);
    k_fill<<<gE, 256, 0, stream>>>(srcp, dstp, row_ptr, wptr, csr_src, E);
    k_bounds<<<1, 64, 0, stream>>>(batch, cnt, offg, N, G);

    k_prep_B<<<D_IN, 256, 0, stream>>>(W1, Bp1, D_IN);
    k_prep_B<<<D_HID, 256, 0, stream>>>(W2, Bp2, D_HID);
    k_prep_B<<<D_HID, 256, 0, stream>>>(W3, Bp3, D_HID);

    int gemm_grid = (N + 63) / 64;

    // layer 1
    k_gemm_mfma<<<gemm_grid, 256, 0, stream>>>(x, Bp1, hA, N, D_IN);
    k_agg<1><<<N, 256, 0, stream>>>(hA, hB, row_ptr, csr_src, dinv, b1);
    // layer 2
    k_gemm_mfma<<<gemm_grid, 256, 0, stream>>>(hB, Bp2, hA, N, D_HID);
    k_agg<1><<<N, 256, 0, stream>>>(hA, hB, row_ptr, csr_src, dinv, b2);
    // layer 3
    k_gemm_mfma<<<gemm_grid, 256, 0, stream>>>(hB, Bp3, hA, N, D_HID);
    k_agg<0><<<N, 256, 0, stream>>>(hA, hB, row_ptr, csr_src, dinv, b3);

    // pool + head
    dim3 pool_grid(G, 8);
    k_pool<<<pool_grid, 256, 0, stream>>>(hB, cnt, offg, gbuf);
    dim3 fin_grid(D_IN / 256, G);
    k_final<<<fin_grid, 256, 0, stream>>>(gbuf, cnt, Wl, bl, out);
}

// Round 5
// 861.330 us; speedup vs baseline: 1.8080x; 1.2706x over previous
//
#include <hip/hip_runtime.h>
#include <hip/hip_bf16.h>

#define D_IN 768
#define D_HID 256

typedef __attribute__((ext_vector_type(8))) short short8;
typedef __attribute__((ext_vector_type(4))) float f32x4;

__device__ inline float b2f(unsigned short u) {
    unsigned x = ((unsigned)u) << 16;
    union { unsigned u; float f; } c; c.u = x; return c.f;
}

// ---------------- CSR build ----------------

__global__ void k_count(const int* __restrict__ dst, int* __restrict__ deg, int E) {
    int i = blockIdx.x * 256 + threadIdx.x;
    if (i < E) atomicAdd(&deg[dst[i]], 1);
}

__global__ void k_dinv(const int* __restrict__ deg, float* __restrict__ dinv, int N) {
    int i = blockIdx.x * 256 + threadIdx.x;
    if (i < N) dinv[i] = rsqrtf((float)deg[i] + 1.0f);
}

// single-block scan over N elements -> exclusive prefix (row_ptr), row_ptr[N]=total
__global__ __launch_bounds__(1024) void k_scan(const int* __restrict__ deg,
                                               int* __restrict__ row_ptr, int N) {
    __shared__ int wsum[16];
    __shared__ int carry_s;
    int t = threadIdx.x;
    int lane = t & 63, wid = t >> 6;
    if (t == 0) carry_s = 0;
    __syncthreads();
    for (int base = 0; base < N; base += 1024) {
        int i = base + t;
        int v = (i < N) ? deg[i] : 0;
        int s = v;
        #pragma unroll
        for (int d = 1; d < 64; d <<= 1) {
            int tmp = __shfl_up(s, d);
            if (lane >= d) s += tmp;
        }
        if (lane == 63) wsum[wid] = s;
        __syncthreads();
        if (wid == 0 && lane < 16) {
            int ws = wsum[lane];
            #pragma unroll
            for (int d = 1; d < 16; d <<= 1) {
                int tmp = __shfl_up(ws, d);
                if (lane >= d) ws += tmp;
            }
            wsum[lane] = ws;  // inclusive over wave sums
        }
        __syncthreads();
        int carry = carry_s;
        int woff = (wid > 0) ? wsum[wid - 1] : 0;
        if (i < N) row_ptr[i] = carry + woff + s - v;
        __syncthreads();
        if (t == 0) carry_s = carry + wsum[15];
        __syncthreads();
    }
    if (t == 0) row_ptr[N] = carry_s;
}

__global__ void k_fill(const int* __restrict__ src, const int* __restrict__ dst,
                       const int* __restrict__ row_ptr, int* __restrict__ wptr,
                       int* __restrict__ csr_src, int E) {
    int i = blockIdx.x * 256 + threadIdx.x;
    if (i < E) {
        int d = dst[i];
        int w = atomicAdd(&wptr[d], 1);
        csr_src[row_ptr[d] + w] = src[i];
    }
}

// batch is SORTED: graph boundaries via binary search — no atomics.
__global__ void k_bounds(const int* __restrict__ batch, int* __restrict__ cnt,
                         int* __restrict__ offg, int N, int G) {
    int g = threadIdx.x;
    if (g >= G) return;
    auto lower = [&](int key) {
        int lo = 0, hi = N;
        while (lo < hi) {
            int mid = (lo + hi) >> 1;
            if (batch[mid] < key) lo = mid + 1; else hi = mid;
        }
        return lo;
    };
    int lo = lower(g);
    int hi = lower(g + 1);
    offg[g] = lo;
    cnt[g] = hi - lo;
}

// ---------------- B prep: fp32 [K][256] -> swizzled bf16 hi/lo fragment order ----
__global__ void k_prep_B(const float* __restrict__ B, short* __restrict__ Bp, int K) {
    int t = blockIdx.x * 256 + threadIdx.x;
    if (t >= K * 256) return;
    int k = t >> 8, n = t & 255;
    float v = B[(size_t)k * 256 + n];
    __hip_bfloat16 h = __float2bfloat16(v);
    float hf = __bfloat162float(h);
    float r = v - hf;
    __hip_bfloat16 l = __float2bfloat16(r);
    int c = k >> 5, q = (k >> 3) & 3, j = k & 7;
    size_t oh = ((size_t)(c * 2 + 0) * 4 + q) * 2048 + n * 8 + j;
    size_t ol = ((size_t)(c * 2 + 1) * 4 + q) * 2048 + n * 8 + j;
    Bp[oh] = *(short*)&h;
    Bp[ol] = *(short*)&l;
}

// ---------------- MFMA GEMM: C[M,256] = A[M,K] @ B[K,256], split-bf16 fp32 emu ---
// BM=64 (4 waves x 16-row strips), BN=256 (full width), BK=32. Output bf16.
__global__ __launch_bounds__(256) void k_gemm_mfma(const float* __restrict__ A,
                                                   const short* __restrict__ Bp,
                                                   unsigned short* __restrict__ C,
                                                   int M, int K) {
    __shared__ short Bs[16384];  // 32 KB per chunk: [f(2)][q(4)][n(256)][j(8)]
    int t = threadIdx.x;
    int lane = t & 63, w = t >> 6;
    int ln = lane & 15, q = lane >> 4;
    int bm = blockIdx.x * 64;
    int m_g = bm + w * 16 + ln;
    bool valid = m_g < M;
    const float* Arow = A + (size_t)(valid ? m_g : 0) * K;

    f32x4 acc[16];
    #pragma unroll
    for (int i = 0; i < 16; ++i) acc[i] = (f32x4){0.f, 0.f, 0.f, 0.f};

    int nchunks = K >> 5;
    for (int c = 0; c < nchunks; ++c) {
        __syncthreads();
        // stage B chunk: 32 KB = 8 iterations x 256 threads x 16 B, fully coalesced
        {
            const short* srcp = Bp + (size_t)c * 16384;
            #pragma unroll
            for (int i = 0; i < 8; ++i) {
                int s = (t + i * 256) * 8;
                *(short8*)&Bs[s] = *(const short8*)&srcp[s];
            }
        }
        // A fragment: 8 contiguous floats, split to bf16 hi/lo in-register
        float av[8];
        if (valid) {
            float4 v0 = *(const float4*)&Arow[c * 32 + q * 8];
            float4 v1 = *(const float4*)&Arow[c * 32 + q * 8 + 4];
            av[0] = v0.x; av[1] = v0.y; av[2] = v0.z; av[3] = v0.w;
            av[4] = v1.x; av[5] = v1.y; av[6] = v1.z; av[7] = v1.w;
        } else {
            #pragma unroll
            for (int i = 0; i < 8; ++i) av[i] = 0.f;
        }
        short8 a_hi, a_lo;
        #pragma unroll
        for (int i = 0; i < 8; ++i) {
            __hip_bfloat16 h = __float2bfloat16(av[i]);
            float hf = __bfloat162float(h);
            __hip_bfloat16 l = __float2bfloat16(av[i] - hf);
            a_hi[i] = *(short*)&h;
            a_lo[i] = *(short*)&l;
        }
        __syncthreads();
        #pragma unroll
        for (int tt = 0; tt < 16; ++tt) {
            short8 b_hi = *(const short8*)&Bs[(0 * 4 + q) * 2048 + (tt * 16 + ln) * 8];
            short8 b_lo = *(const short8*)&Bs[(1 * 4 + q) * 2048 + (tt * 16 + ln) * 8];
            acc[tt] = __builtin_amdgcn_mfma_f32_16x16x32_bf16(a_hi, b_hi, acc[tt], 0, 0, 0);
            acc[tt] = __builtin_amdgcn_mfma_f32_16x16x32_bf16(a_hi, b_lo, acc[tt], 0, 0, 0);
            acc[tt] = __builtin_amdgcn_mfma_f32_16x16x32_bf16(a_lo, b_hi, acc[tt], 0, 0, 0);
        }
    }
    // C/D layout: col = tt*16 + (lane&15), row = w*16 + (lane>>4)*4 + r
    #pragma unroll
    for (int tt = 0; tt < 16; ++tt) {
        #pragma unroll
        for (int r = 0; r < 4; ++r) {
            int row = bm + w * 16 + q * 4 + r;
            if (row < M) {
                __hip_bfloat16 h = __float2bfloat16(acc[tt][r]);
                C[(size_t)row * 256 + tt * 16 + ln] = *(unsigned short*)&h;
            }
        }
    }
}

// ---------------- aggregation: one wave per dst row, bf16 gather ----------------
template <int RELU>
__global__ __launch_bounds__(256) void k_agg(const unsigned short* __restrict__ hin,
                                             float* __restrict__ hout,
                                             const int* __restrict__ row_ptr,
                                             const int* __restrict__ csr_src,
                                             const float* __restrict__ dinv,
                                             const float* __restrict__ bias, int N) {
    int w = threadIdx.x >> 6;
    int lane = threadIdx.x & 63;
    int row = blockIdx.x * 4 + w;
    if (row >= N) return;
    int c4 = lane * 4;
    int s = row_ptr[row], e = row_ptr[row + 1];
    float a0 = 0.f, a1 = 0.f, a2 = 0.f, a3 = 0.f;
    int j = s;
    for (; j + 4 <= e; j += 4) {
        int u0 = csr_src[j], u1 = csr_src[j + 1], u2 = csr_src[j + 2], u3 = csr_src[j + 3];
        float d0 = dinv[u0], d1 = dinv[u1], d2 = dinv[u2], d3 = dinv[u3];
        ushort4 v0 = *(const ushort4*)&hin[(size_t)u0 * 256 + c4];
        ushort4 v1 = *(const ushort4*)&hin[(size_t)u1 * 256 + c4];
        ushort4 v2 = *(const ushort4*)&hin[(size_t)u2 * 256 + c4];
        ushort4 v3 = *(const ushort4*)&hin[(size_t)u3 * 256 + c4];
        a0 += d0 * b2f(v0.x) + d1 * b2f(v1.x) + d2 * b2f(v2.x) + d3 * b2f(v3.x);
        a1 += d0 * b2f(v0.y) + d1 * b2f(v1.y) + d2 * b2f(v2.y) + d3 * b2f(v3.y);
        a2 += d0 * b2f(v0.z) + d1 * b2f(v1.z) + d2 * b2f(v2.z) + d3 * b2f(v3.z);
        a3 += d0 * b2f(v0.w) + d1 * b2f(v1.w) + d2 * b2f(v2.w) + d3 * b2f(v3.w);
    }
    for (; j < e; ++j) {
        int u = csr_src[j];
        float d = dinv[u];
        ushort4 v = *(const ushort4*)&hin[(size_t)u * 256 + c4];
        a0 += d * b2f(v.x); a1 += d * b2f(v.y); a2 += d * b2f(v.z); a3 += d * b2f(v.w);
    }
    float di = dinv[row];
    float dii = di * di;
    ushort4 vs = *(const ushort4*)&hin[(size_t)row * 256 + c4];
    float4 bb = *(const float4*)&bias[c4];
    a0 = a0 * di + dii * b2f(vs.x) + bb.x;
    a1 = a1 * di + dii * b2f(vs.y) + bb.y;
    a2 = a2 * di + dii * b2f(vs.z) + bb.z;
    a3 = a3 * di + dii * b2f(vs.w) + bb.w;
    if (RELU) {
        a0 = fmaxf(a0, 0.f); a1 = fmaxf(a1, 0.f);
        a2 = fmaxf(a2, 0.f); a3 = fmaxf(a3, 0.f);
    }
    *(float4*)&hout[(size_t)row * 256 + c4] = make_float4(a0, a1, a2, a3);
}

// ---------------- pool ----------------
__global__ __launch_bounds__(256) void k_pool(const float* __restrict__ h,
                                              const int* __restrict__ cnt,
                                              const int* __restrict__ offg,
                                              float* __restrict__ g) {
    int gi = blockIdx.x, slice = blockIdx.y;
    int c = threadIdx.x;
    int start = offg[gi], n = cnt[gi];
    int per = (n + (int)gridDim.y - 1) / (int)gridDim.y;
    int r0 = slice * per;
    int r1 = min(n, r0 + per);
    float acc = 0.f;
    for (int r = r0; r < r1; ++r) acc += h[(size_t)(start + r) * D_HID + c];
    if (r1 > r0) atomicAdd(&g[gi * D_HID + c], acc);
}

// ---------------- head ----------------
__global__ __launch_bounds__(256) void k_final(const float* __restrict__ g,
                                               const int* __restrict__ cnt,
                                               const float* __restrict__ Wl,
                                               const float* __restrict__ bl,
                                               float* __restrict__ out) {
    __shared__ float gs[D_HID];
    int t = threadIdx.x;
    int gi = blockIdx.y;
    int c = blockIdx.x * 256 + t;
    float inv = 1.0f / (float)max(cnt[gi], 1);
    gs[t] = g[gi * D_HID + t] * inv;
    __syncthreads();
    float acc = bl[c];
    #pragma unroll 8
    for (int k = 0; k < D_HID; ++k) acc = fmaf(gs[k], Wl[(size_t)k * D_IN + c], acc);
    out[(size_t)gi * D_IN + c] = acc;
}

// ---------------- launch ----------------

extern "C" void kernel_launch(void* const* d_in, const int* in_sizes, int n_in,
                              void* d_out, int out_size, void* d_ws, size_t ws_size,
                              hipStream_t stream) {
    const float* x     = (const float*)d_in[0];
    const int*   ei    = (const int*)d_in[1];
    const int*   batch = (const int*)d_in[2];
    const float* W1 = (const float*)d_in[3];
    const float* b1 = (const float*)d_in[4];
    const float* W2 = (const float*)d_in[5];
    const float* b2 = (const float*)d_in[6];
    const float* W3 = (const float*)d_in[7];
    const float* b3 = (const float*)d_in[8];
    const float* Wl = (const float*)d_in[9];
    const float* bl = (const float*)d_in[10];
    float* out = (float*)d_out;

    int N = in_sizes[2];
    int E = in_sizes[1] / 2;
    int G = out_size / D_IN;
    const int* srcp = ei;
    const int* dstp = ei + E;

    char* ws = (char*)d_ws;
    size_t o = 0;
    auto alloc = [&](size_t bytes) -> char* {
        char* p = ws + o;
        o += (bytes + 255) & ~(size_t)255;
        return p;
    };
    int*   deg     = (int*)alloc((size_t)N * 4);
    int*   wptr    = (int*)alloc((size_t)N * 4);
    int*   row_ptr = (int*)alloc((size_t)(N + 1) * 4);
    int*   cnt     = (int*)alloc((size_t)G * 4);
    int*   offg    = (int*)alloc((size_t)G * 4);
    int*   csr_src = (int*)alloc((size_t)E * 4);
    float* dinv    = (float*)alloc((size_t)N * 4);
    float* gbuf    = (float*)alloc((size_t)G * D_HID * 4);
    unsigned short* hA = (unsigned short*)alloc((size_t)N * D_HID * 2);  // bf16 h
    float* hB      = (float*)alloc((size_t)N * D_HID * 4);
    short* Bp1     = (short*)alloc((size_t)D_IN * 512 * 2);   // K=768 swizzled hi/lo
    short* Bp2     = (short*)alloc((size_t)D_HID * 512 * 2);  // K=256
    short* Bp3     = (short*)alloc((size_t)D_HID * 512 * 2);

    hipMemsetAsync(deg, 0, (size_t)N * 4, stream);
    hipMemsetAsync(wptr, 0, (size_t)N * 4, stream);
    hipMemsetAsync(gbuf, 0, (size_t)G * D_HID * 4, stream);

    int gE = (E + 255) / 256;
    int gN = (N + 255) / 256;

    k_count<<<gE, 256, 0, stream>>>(dstp, deg, E);
    k_dinv<<<gN, 256, 0, stream>>>(deg, dinv, N);
    k_scan<<<1, 1024, 0, stream>>>(deg, row_ptr, N);
    k_fill<<<gE, 256, 0, stream>>>(srcp, dstp, row_ptr, wptr, csr_src, E);
    k_bounds<<<1, 64, 0, stream>>>(batch, cnt, offg, N, G);

    k_prep_B<<<D_IN, 256, 0, stream>>>(W1, Bp1, D_IN);
    k_prep_B<<<D_HID, 256, 0, stream>>>(W2, Bp2, D_HID);
    k_prep_B<<<D_HID, 256, 0, stream>>>(W3, Bp3, D_HID);

    int gemm_grid = (N + 63) / 64;
    int agg_grid = (N + 3) / 4;

    // layer 1
    k_gemm_mfma<<<gemm_grid, 256, 0, stream>>>(x, Bp1, hA, N, D_IN);
    k_agg<1><<<agg_grid, 256, 0, stream>>>(hA, hB, row_ptr, csr_src, dinv, b1, N);
    // layer 2
    k_gemm_mfma<<<gemm_grid, 256, 0, stream>>>(hB, Bp2, hA, N, D_HID);
    k_agg<1><<<agg_grid, 256, 0, stream>>>(hA, hB, row_ptr, csr_src, dinv, b2, N);
    // layer 3
    k_gemm_mfma<<<gemm_grid, 256, 0, stream>>>(hB, Bp3, hA, N, D_HID);
    k_agg<0><<<agg_grid, 256, 0, stream>>>(hA, hB, row_ptr, csr_src, dinv, b3, N);

    // pool + head
    dim3 pool_grid(G, 8);
    k_pool<<<pool_grid, 256, 0, stream>>>(hB, cnt, offg, gbuf);
    dim3 fin_grid(D_IN / 256, G);
    k_final<<<fin_grid, 256, 0, stream>>>(gbuf, cnt, Wl, bl, out);
}